// Round 7
// baseline (686.888 us; speedup 1.0000x reference)
//
#include <hip/hip_runtime.h>
#include <hip/hip_bf16.h>
#include <hip/hip_fp16.h>

#define N_NODES 20000
#define E_EDGES 320000
#define CIN 128
#define HDIM 128
#define EDGE_DIM 16
#define SDIM 3
#define KS 3
#define KK 27           // 3^3 kernel weight matrices
#define NB 28           // 27 spline blocks + 1 root-weight block
#define ZLD (NB * 128)  // Z leading dim = 3584 elements (bf16)
#define S_TAPS 8
#define MLP_HID 6
#define MT_TOTAL (N_NODES / 16)   // 1250 m-tiles of 16 rows

typedef __attribute__((ext_vector_type(8))) short v8s;   // 8 bf16 (4 VGPRs)
typedef __attribute__((ext_vector_type(4))) float v4f;   // MFMA accumulator
typedef unsigned short ush;
typedef unsigned char uch;

static __device__ __forceinline__ short f2bf(float v) {
    unsigned u = __float_as_uint(v);
    unsigned r = (u + 0x7fffu + ((u >> 16) & 1u)) >> 16;   // RTNE
    return (short)r;
}
static __device__ __forceinline__ float bf2f(unsigned s) {
    return __uint_as_float((s & 0xffffu) << 16);
}
static __device__ __forceinline__ float bf2f_lo(unsigned u) {   // low bf16 of a packed pair
    return __uint_as_float(u << 16);
}
static __device__ __forceinline__ float bf2f_hi(unsigned u) {   // high bf16 of a packed pair
    return __uint_as_float(u & 0xffff0000u);
}
static __device__ __forceinline__ unsigned short f2h(float f) {
    __half h = __float2half(f);
    return __half_as_ushort(h);
}
static __device__ __forceinline__ float h2f(unsigned u) {
    __half_raw r; r.x = (unsigned short)u;
    return __half2float(__half(r));
}

// ---------------------------------------------------------------------------
// edge_index dtype detect + decode (int64 vs int32 storage)
// ---------------------------------------------------------------------------
__global__ void detect_kernel(const unsigned int* __restrict__ e, int* __restrict__ flag) {
    __shared__ int s_nz;
    if (threadIdx.x == 0) s_nz = 0;
    __syncthreads();
    unsigned int v = e[threadIdx.x * 2 + 1];
    if (v != 0) atomicAdd(&s_nz, 1);
    __syncthreads();
    if (threadIdx.x == 0) *flag = (s_nz > 0) ? 1 : 0;
}

__global__ void decode_edges(const void* __restrict__ eraw, const int* __restrict__ flag,
                             int* __restrict__ e32, int n) {
    int i = blockIdx.x * blockDim.x + threadIdx.x;
    if (i >= n) return;
    if (*flag) e32[i] = ((const int*)eraw)[i];
    else       e32[i] = (int)(((const long long*)eraw)[i]);
}

// ---------------------------------------------------------------------------
// Edge MLP (16->6 relu ->3 sigmoid) + degree-1 open B-spline basis.
// Emits fp16 weights (wq[E][8]) and byte kernel indices (kq[E][8]).
// ---------------------------------------------------------------------------
__global__ void edge_basis(const float* __restrict__ ea,
                           const float* __restrict__ Wp1, const float* __restrict__ bp1,
                           const float* __restrict__ Wp2, const float* __restrict__ bp2,
                           ush* __restrict__ wq, uch* __restrict__ kq) {
    __shared__ float sW1[EDGE_DIM * MLP_HID];
    __shared__ float sb1[MLP_HID];
    __shared__ float sW2[MLP_HID * SDIM];
    __shared__ float sb2[SDIM];
    int t = threadIdx.x;
    if (t < EDGE_DIM * MLP_HID) sW1[t] = Wp1[t];
    if (t < MLP_HID)            sb1[t] = bp1[t];
    if (t < MLP_HID * SDIM)     sW2[t] = Wp2[t];
    if (t < SDIM)               sb2[t] = bp2[t];
    __syncthreads();
    int e = blockIdx.x * blockDim.x + t;
    if (e >= E_EDGES) return;

    float a[EDGE_DIM];
#pragma unroll
    for (int i = 0; i < EDGE_DIM; i++) a[i] = ea[(long)e * EDGE_DIM + i];

    float hid[MLP_HID];
#pragma unroll
    for (int j = 0; j < MLP_HID; j++) {
        float s = sb1[j];
#pragma unroll
        for (int i = 0; i < EDGE_DIM; i++) s += a[i] * sW1[i * MLP_HID + j];
        hid[j] = fmaxf(s, 0.f);
    }

    float lo[SDIM], fr[SDIM];
#pragma unroll
    for (int d = 0; d < SDIM; d++) {
        float s = sb2[d];
#pragma unroll
        for (int j = 0; j < MLP_HID; j++) s += hid[j] * sW2[j * SDIM + d];
        float u = 1.f / (1.f + expf(-s));
        float v = u * (float)(KS - 1);
        float l = floorf(v);
        l = fminf(fmaxf(l, 0.f), (float)(KS - 2));
        lo[d] = l;
        fr[d] = v - l;
    }

#pragma unroll
    for (int s = 0; s < S_TAPS; s++) {
        float w = 1.f;
        int idx = 0, stride = 1;
#pragma unroll
        for (int d = 0; d < SDIM; d++) {
            int bit = (s >> d) & 1;
            w *= bit ? fr[d] : (1.f - fr[d]);
            idx += ((int)lo[d] + bit) * stride;
            stride *= KS;
        }
        wq[(long)e * S_TAPS + s] = f2h(w);
        kq[(long)e * S_TAPS + s] = (uch)idx;
    }
}

// ---------------------------------------------------------------------------
// CSR build binned by (dst, src-chunk) — built once, reused for 3 layers
// ---------------------------------------------------------------------------
__global__ void zero_int(int* __restrict__ p, int n) {
    int i = blockIdx.x * blockDim.x + threadIdx.x;
    if (i < n) p[i] = 0;
}

__global__ void hist2_kernel(const int* __restrict__ dst, const int* __restrict__ src,
                             int* __restrict__ hist, int nc, int chunk_rows) {
    int e = blockIdx.x * blockDim.x + threadIdx.x;
    if (e >= E_EDGES) return;
    int bin = dst[e] * nc + src[e] / chunk_rows;
    atomicAdd(&hist[bin], 1);
}

__global__ void scan_kernel(const int* __restrict__ hist, int* __restrict__ rowptr, int B) {
    __shared__ int part[256];
    int t = threadIdx.x;
    const int per = (B + 255) / 256;
    int base = t * per;
    int s = 0;
    for (int i = 0; i < per; i++) {
        int idx = base + i;
        if (idx < B) s += hist[idx];
    }
    part[t] = s;
    __syncthreads();
    for (int off = 1; off < 256; off <<= 1) {
        int v = (t >= off) ? part[t - off] : 0;
        __syncthreads();
        part[t] += v;
        __syncthreads();
    }
    int run = (t == 0) ? 0 : part[t - 1];
    for (int i = 0; i < per; i++) {
        int idx = base + i;
        if (idx < B) { rowptr[idx] = run; run += hist[idx]; }
    }
    if (t == 255) rowptr[B] = run;
}

__global__ void perm2_kernel(const int* __restrict__ dst, const int* __restrict__ src,
                             const int* __restrict__ rowptr, int* __restrict__ cursor,
                             int* __restrict__ eperm, int nc, int chunk_rows) {
    int e = blockIdx.x * blockDim.x + threadIdx.x;
    if (e >= E_EDGES) return;
    int bin = dst[e] * nc + src[e] / chunk_rows;
    int pos = rowptr[bin] + atomicAdd(&cursor[bin], 1);
    eperm[pos] = e;
}

// Pack metadata into CSR order: sequential streaming in the gather.
__global__ void pack_csr(const int* __restrict__ eperm, const int* __restrict__ src,
                         const ush* __restrict__ wq, const uch* __restrict__ kq,
                         int* __restrict__ srcp, ush* __restrict__ wp, uch* __restrict__ kp) {
    int j = blockIdx.x * blockDim.x + threadIdx.x;
    if (j >= E_EDGES) return;
    int e = eperm[j];
    srcp[j] = src[e];
    *(uint4*)(wp + (size_t)j * 8) = *(const uint4*)(wq + (size_t)e * 8);
    *(uint2*)(kp + (size_t)j * 8) = *(const uint2*)(kq + (size_t)e * 8);
}

// ---------------------------------------------------------------------------
// Convert activations -> bf16 hi/lo in MFMA A-fragment layout.
// ---------------------------------------------------------------------------
__global__ void convA_kernel(const float* __restrict__ A, short* __restrict__ hi,
                             short* __restrict__ lo, int do_relu) {
    int gid = blockIdx.x * blockDim.x + threadIdx.x;
    if (gid >= MT_TOTAL * 4 * 64) return;
    int lane = gid & 63;
    int ks = (gid >> 6) & 3;
    int mt = gid >> 8;
    int row = mt * 16 + (lane & 15);
    int col = ks * 32 + ((lane >> 4) & 3) * 8;
    const float* p = A + (long)row * CIN + col;
    long off = ((long)(mt * 4 + ks) * 64 + lane) * 8;
#pragma unroll
    for (int j = 0; j < 8; j++) {
        float v = p[j];
        if (do_relu) v = fmaxf(v, 0.f);
        short h = f2bf(v);
        float r = v - bf2f((unsigned short)h);
        hi[off + j] = h;
        lo[off + j] = f2bf(r);
    }
}

// ---------------------------------------------------------------------------
// Pack [W (27 blocks) | Wr] -> bf16 in MFMA B-fragment layout (hi only).
// ---------------------------------------------------------------------------
__global__ void packW_kernel(const float* __restrict__ W, const float* __restrict__ Wr,
                             short* __restrict__ hi) {
    int gid = blockIdx.x * blockDim.x + threadIdx.x;
    if (gid >= NB * 4 * 8 * 64) return;
    int lane = gid & 63;
    int nt = (gid >> 6) & 7;
    int ks = (gid >> 9) & 3;
    int kb = gid >> 11;
    int i0 = ks * 32 + ((lane >> 4) & 3) * 8;
    int o = nt * 16 + (lane & 15);
    const float* src = (kb < KK) ? (W + (long)kb * 16384 + (long)i0 * 128 + o)
                                 : (Wr + (long)i0 * 128 + o);
    long off = ((long)((kb * 4 + ks) * 8 + nt) * 64 + lane) * 8;
#pragma unroll
    for (int j = 0; j < 8; j++) {
        float v = src[(long)j * 128];
        hi[off + j] = f2bf(v);
    }
}

// ---------------------------------------------------------------------------
// MFMA GEMM: Z[row-row_lo, kb*128+o] = sum_i A[row,i]*B[kb][i][o]  (bf16 out)
// Split-bf16 2-pass on A (AhiB + AloB); W plain bf16.
// grid = (kb=NB fast, m-group) for A-slice L2 locality.
// ---------------------------------------------------------------------------
__global__ __launch_bounds__(256) void gemm_kernel(
    const short* __restrict__ Ah, const short* __restrict__ Al,
    const short* __restrict__ Wh,
    ush* __restrict__ Z, int mtile_lo, int mtile_hi, int row_lo, int row_hi)
{
    int wave = threadIdx.x >> 6;
    int lane = threadIdx.x & 63;
    int kb = blockIdx.x;                               // fast-varying -> A locality
    int mt0 = mtile_lo + blockIdx.y * 8 + wave * 2;
    if (mt0 >= mtile_hi) return;
    int mt1 = (mt0 + 1 < mtile_hi) ? (mt0 + 1) : mt0;

    v4f acc[2][8];
#pragma unroll
    for (int m = 0; m < 2; m++)
#pragma unroll
        for (int n = 0; n < 8; n++) acc[m][n] = (v4f){0.f, 0.f, 0.f, 0.f};

#pragma unroll
    for (int ks = 0; ks < 4; ks++) {
        long a0 = ((long)(mt0 * 4 + ks) * 64 + lane) * 8;
        long a1 = ((long)(mt1 * 4 + ks) * 64 + lane) * 8;
        v8s ah0 = *(const v8s*)(Ah + a0);
        v8s al0 = *(const v8s*)(Al + a0);
        v8s ah1 = *(const v8s*)(Ah + a1);
        v8s al1 = *(const v8s*)(Al + a1);
#pragma unroll
        for (int nt = 0; nt < 8; nt++) {
            long boff = ((long)((kb * 4 + ks) * 8 + nt) * 64 + lane) * 8;
            v8s bh = *(const v8s*)(Wh + boff);
            acc[0][nt] = __builtin_amdgcn_mfma_f32_16x16x32_bf16(ah0, bh, acc[0][nt], 0, 0, 0);
            acc[0][nt] = __builtin_amdgcn_mfma_f32_16x16x32_bf16(al0, bh, acc[0][nt], 0, 0, 0);
            acc[1][nt] = __builtin_amdgcn_mfma_f32_16x16x32_bf16(ah1, bh, acc[1][nt], 0, 0, 0);
            acc[1][nt] = __builtin_amdgcn_mfma_f32_16x16x32_bf16(al1, bh, acc[1][nt], 0, 0, 0);
        }
    }

    // C/D layout: col = lane&15, row-in-tile = (lane>>4)*4 + reg
#pragma unroll
    for (int m = 0; m < 2; m++) {
        int mtg = mt0 + m;
        if (mtg >= mtile_hi) break;
#pragma unroll
        for (int nt = 0; nt < 8; nt++) {
            int col = kb * 128 + nt * 16 + (lane & 15);
#pragma unroll
            for (int r = 0; r < 4; r++) {
                int row = mtg * 16 + ((lane >> 4) & 3) * 4 + r;
                if (row >= row_hi) continue;
                Z[(size_t)(row - row_lo) * ZLD + col] = (ush)f2bf(acc[m][nt][r]);
            }
        }
    }
}

// ---------------------------------------------------------------------------
// Gather v3: one wave per dst node. Lane = (tap t = lane&7) x (ch-group
// g = lane>>3, 16 channels). Per edge: 2x global_load_dwordx4 fetch the
// full 8-tap x 128-ch (2 KB) slab; 16 fma/lane. Tap reduction once per
// node via 3 xor-shuffles (masks 1,2,4 — intra-row, cheap). t==0 lanes
// (8 of them, 16 ch each) do root + bias + store.
// ---------------------------------------------------------------------------
__global__ __launch_bounds__(256) void gather3_kernel(
    const ush* __restrict__ Z, const int* __restrict__ rowptr,
    const int* __restrict__ srcp, const ush* __restrict__ wp,
    const uch* __restrict__ kp, const float* __restrict__ bias,
    float* __restrict__ outp, int lo, int hi, int nc, int cidx, int first)
{
    int wave = threadIdx.x >> 6;
    int lane = threadIdx.x & 63;
    int n = blockIdx.x * 4 + wave;
    int t = lane & 7;          // tap index
    int g = lane >> 3;         // channel group
    int cb = g * 16;           // first channel of this lane's group

    int bin = n * nc + cidx;
    int jb = rowptr[bin], je = rowptr[bin + 1];

    float acc[16];
#pragma unroll
    for (int i = 0; i < 16; i++) acc[i] = 0.f;

#pragma unroll 2
    for (int j = jb; j < je; j++) {
        int s = srcp[j];
        float w = h2f(wp[(size_t)j * 8 + t]);
        int k = kp[(size_t)j * 8 + t];
        const ush* zb = Z + (size_t)(s - lo) * ZLD + k * 128 + cb;
        uint4 z0 = *(const uint4*)(zb);       // ch cb+0 .. cb+7
        uint4 z1 = *(const uint4*)(zb + 8);   // ch cb+8 .. cb+15
        acc[0]  += w * bf2f_lo(z0.x);  acc[1]  += w * bf2f_hi(z0.x);
        acc[2]  += w * bf2f_lo(z0.y);  acc[3]  += w * bf2f_hi(z0.y);
        acc[4]  += w * bf2f_lo(z0.z);  acc[5]  += w * bf2f_hi(z0.z);
        acc[6]  += w * bf2f_lo(z0.w);  acc[7]  += w * bf2f_hi(z0.w);
        acc[8]  += w * bf2f_lo(z1.x);  acc[9]  += w * bf2f_hi(z1.x);
        acc[10] += w * bf2f_lo(z1.y);  acc[11] += w * bf2f_hi(z1.y);
        acc[12] += w * bf2f_lo(z1.z);  acc[13] += w * bf2f_hi(z1.z);
        acc[14] += w * bf2f_lo(z1.w);  acc[15] += w * bf2f_hi(z1.w);
    }

    // Reduce over the 8 taps (lanes differing in bits 0..2).
#pragma unroll
    for (int m = 1; m <= 4; m <<= 1) {
#pragma unroll
        for (int i = 0; i < 16; i++) acc[i] += __shfl_xor(acc[i], m, 64);
    }

    if (t == 0) {
        if (n >= lo && n < hi) {   // root weight + bias (chunk owning node n)
            const ush* zr = Z + (size_t)(n - lo) * ZLD + KK * 128 + cb;
            uint4 r0 = *(const uint4*)(zr);
            uint4 r1 = *(const uint4*)(zr + 8);
            const float4* bp4 = (const float4*)(bias + cb);
            float4 b0 = bp4[0], b1 = bp4[1], b2 = bp4[2], b3 = bp4[3];
            acc[0]  += bf2f_lo(r0.x) + b0.x;  acc[1]  += bf2f_hi(r0.x) + b0.y;
            acc[2]  += bf2f_lo(r0.y) + b0.z;  acc[3]  += bf2f_hi(r0.y) + b0.w;
            acc[4]  += bf2f_lo(r0.z) + b1.x;  acc[5]  += bf2f_hi(r0.z) + b1.y;
            acc[6]  += bf2f_lo(r0.w) + b1.z;  acc[7]  += bf2f_hi(r0.w) + b1.w;
            acc[8]  += bf2f_lo(r1.x) + b2.x;  acc[9]  += bf2f_hi(r1.x) + b2.y;
            acc[10] += bf2f_lo(r1.y) + b2.z;  acc[11] += bf2f_hi(r1.y) + b2.w;
            acc[12] += bf2f_lo(r1.z) + b3.x;  acc[13] += bf2f_hi(r1.z) + b3.y;
            acc[14] += bf2f_lo(r1.w) + b3.z;  acc[15] += bf2f_hi(r1.w) + b3.w;
        }
        float* op = outp + (size_t)n * HDIM + cb;
        if (!first) {
            const float4* o4 = (const float4*)op;
#pragma unroll
            for (int q = 0; q < 4; q++) {
                float4 ov = o4[q];
                acc[q * 4 + 0] += ov.x; acc[q * 4 + 1] += ov.y;
                acc[q * 4 + 2] += ov.z; acc[q * 4 + 3] += ov.w;
            }
        }
#pragma unroll
        for (int q = 0; q < 4; q++) {
            float4 ov = make_float4(acc[q * 4 + 0], acc[q * 4 + 1],
                                    acc[q * 4 + 2], acc[q * 4 + 3]);
            ((float4*)op)[q] = ov;
        }
    }
}

// ---------------------------------------------------------------------------
extern "C" void kernel_launch(void* const* d_in, const int* in_sizes, int n_in,
                              void* d_out, int out_size, void* d_ws, size_t ws_size,
                              hipStream_t stream) {
    const float* x   = (const float*)d_in[0];
    const void*  eix = d_in[1];
    const float* ea  = (const float*)d_in[2];
    const float* Wp1 = (const float*)d_in[3];
    const float* bp1 = (const float*)d_in[4];
    const float* Wp2 = (const float*)d_in[5];
    const float* bp2 = (const float*)d_in[6];
    const float* W[3]  = {(const float*)d_in[7],  (const float*)d_in[10], (const float*)d_in[13]};
    const float* Wr[3] = {(const float*)d_in[8],  (const float*)d_in[11], (const float*)d_in[14]};
    const float* b[3]  = {(const float*)d_in[9],  (const float*)d_in[12], (const float*)d_in[15]};
    float* out = (float*)d_out;

    char* ws = (char*)d_ws;
    size_t off = 0;
    auto walloc = [&](size_t bytes) -> void* {
        void* p = ws + off;
        off = (off + bytes + 255) & ~(size_t)255;
        return p;
    };
    int*   flag   = (int*)  walloc(sizeof(int));
    int*   e32    = (int*)  walloc(sizeof(int) * 2 * E_EDGES);
    ush*   wq     = (ush*)  walloc(sizeof(ush) * (size_t)E_EDGES * 8);
    uch*   kq     = (uch*)  walloc((size_t)E_EDGES * 8);
    float* h0     = (float*)walloc(sizeof(float) * (size_t)N_NODES * HDIM);
    float* h1     = (float*)walloc(sizeof(float) * (size_t)N_NODES * HDIM);
    short* Ah     = (short*)walloc(sizeof(short) * (size_t)N_NODES * CIN);
    short* Al     = (short*)walloc(sizeof(short) * (size_t)N_NODES * CIN);
    short* Wh     = (short*)walloc(sizeof(short) * (size_t)NB * 128 * 128);
    int*   eperm  = (int*)  walloc(sizeof(int) * E_EDGES);
    int*   srcp   = (int*)  walloc(sizeof(int) * E_EDGES);
    ush*   wp     = (ush*)  walloc(sizeof(ush) * (size_t)E_EDGES * 8);
    uch*   kp     = (uch*)  walloc((size_t)E_EDGES * 8);

    // Pick the smallest chunk count nc such that CSR arrays + Z fit.
    int  nc = -1;
    long chunk_rows = 0;
    for (int t = 1; t <= 157; t++) {
        long cr = (((N_NODES + t - 1) / t) + 127) / 128 * 128;
        size_t bins = (size_t)N_NODES * t;
        size_t need = 0;
        auto a = [&](size_t bb) { need += (bb + 255) & ~(size_t)255; };
        a(sizeof(int) * bins);             // hist
        a(sizeof(int) * bins);             // cursor
        a(sizeof(int) * (bins + 1));       // rowptr
        a((size_t)cr * ZLD * sizeof(ush)); // Z
        if (off + need <= ws_size) { nc = t; chunk_rows = cr; break; }
    }
    if (nc < 0) { nc = 157; chunk_rows = 128; }
    size_t bins = (size_t)N_NODES * nc;
    int*   hist   = (int*)walloc(sizeof(int) * bins);
    int*   cursor = (int*)walloc(sizeof(int) * bins);
    int*   rowptr = (int*)walloc(sizeof(int) * (bins + 1));
    ush*   Z      = (ush*)walloc((size_t)chunk_rows * ZLD * sizeof(ush));

    int* srcv = e32;
    int* dstv = e32 + E_EDGES;

    detect_kernel<<<1, 1024, 0, stream>>>((const unsigned int*)eix, flag);
    decode_edges<<<(2 * E_EDGES + 255) / 256, 256, 0, stream>>>(eix, flag, e32, 2 * E_EDGES);
    edge_basis<<<(E_EDGES + 255) / 256, 256, 0, stream>>>(ea, Wp1, bp1, Wp2, bp2, wq, kq);

    // CSR binned by (dst, src-chunk); built once, reused across 3 layers
    zero_int<<<((int)bins + 255) / 256, 256, 0, stream>>>(hist, (int)bins);
    zero_int<<<((int)bins + 255) / 256, 256, 0, stream>>>(cursor, (int)bins);
    hist2_kernel<<<(E_EDGES + 255) / 256, 256, 0, stream>>>(dstv, srcv, hist, nc, (int)chunk_rows);
    scan_kernel<<<1, 256, 0, stream>>>(hist, rowptr, (int)bins);
    perm2_kernel<<<(E_EDGES + 255) / 256, 256, 0, stream>>>(dstv, srcv, rowptr, cursor,
                                                            eperm, nc, (int)chunk_rows);
    pack_csr<<<(E_EDGES + 255) / 256, 256, 0, stream>>>(eperm, srcv, wq, kq, srcp, wp, kp);

    const float* lin[3]  = {x, h0, h1};
    float*       lout[3] = {h0, h1, out};

    for (int l = 0; l < 3; l++) {
        convA_kernel<<<(MT_TOTAL * 4 * 64 + 255) / 256, 256, 0, stream>>>(
            lin[l], Ah, Al, (l > 0) ? 1 : 0);
        packW_kernel<<<(NB * 4 * 8 * 64 + 255) / 256, 256, 0, stream>>>(
            W[l], Wr[l], Wh);
        for (int c = 0; c < nc; c++) {
            long lo = (long)c * chunk_rows;
            long hi = lo + chunk_rows;
            if (hi > N_NODES) hi = N_NODES;
            if (lo >= N_NODES) break;
            int mtile_lo = (int)(lo / 16);
            int mtile_hi = (int)((hi + 15) / 16);
            int gy = (mtile_hi - mtile_lo + 7) / 8;
            dim3 grid(NB, gy);
            gemm_kernel<<<grid, 256, 0, stream>>>(Ah, Al, Wh, Z,
                                                  mtile_lo, mtile_hi, (int)lo, (int)hi);
            gather3_kernel<<<N_NODES / 4, 256, 0, stream>>>(
                Z, rowptr, srcp, wp, kp, b[l], lout[l],
                (int)lo, (int)hi, nc, c, (c == 0) ? 1 : 0);
        }
    }
}

// Round 8
// 675.040 us; speedup vs baseline: 1.0176x; 1.0176x over previous
//
#include <hip/hip_runtime.h>
#include <hip/hip_bf16.h>
#include <hip/hip_fp16.h>

#define N_NODES 20000
#define E_EDGES 320000
#define CIN 128
#define HDIM 128
#define EDGE_DIM 16
#define SDIM 3
#define KS 3
#define KK 27           // 3^3 kernel weight matrices
#define NB 28           // 27 spline blocks + 1 root-weight block
#define ZLD (NB * 128)  // Z leading dim = 3584 elements (bf16)
#define S_TAPS 8
#define MLP_HID 6
#define MT_TOTAL (N_NODES / 16)   // 1250 m-tiles of 16 rows

typedef __attribute__((ext_vector_type(8))) short v8s;   // 8 bf16 (4 VGPRs)
typedef __attribute__((ext_vector_type(4))) float v4f;   // MFMA accumulator
typedef unsigned short ush;
typedef unsigned char uch;

static __device__ __forceinline__ short f2bf(float v) {
    unsigned u = __float_as_uint(v);
    unsigned r = (u + 0x7fffu + ((u >> 16) & 1u)) >> 16;   // RTNE
    return (short)r;
}
static __device__ __forceinline__ float bf2f(unsigned s) {
    return __uint_as_float((s & 0xffffu) << 16);
}
static __device__ __forceinline__ float bf2f_lo(unsigned u) {   // low bf16 of a packed pair
    return __uint_as_float(u << 16);
}
static __device__ __forceinline__ float bf2f_hi(unsigned u) {   // high bf16 of a packed pair
    return __uint_as_float(u & 0xffff0000u);
}
static __device__ __forceinline__ unsigned short f2h(float f) {
    __half h = __float2half(f);
    return __half_as_ushort(h);
}
static __device__ __forceinline__ float h2f(unsigned u) {
    __half_raw r; r.x = (unsigned short)u;
    return __half2float(__half(r));
}

// ---------------------------------------------------------------------------
// edge_index dtype detect + decode (int64 vs int32 storage)
// ---------------------------------------------------------------------------
__global__ void detect_kernel(const unsigned int* __restrict__ e, int* __restrict__ flag) {
    __shared__ int s_nz;
    if (threadIdx.x == 0) s_nz = 0;
    __syncthreads();
    unsigned int v = e[threadIdx.x * 2 + 1];
    if (v != 0) atomicAdd(&s_nz, 1);
    __syncthreads();
    if (threadIdx.x == 0) *flag = (s_nz > 0) ? 1 : 0;
}

__global__ void decode_edges(const void* __restrict__ eraw, const int* __restrict__ flag,
                             int* __restrict__ e32, int n) {
    int i = blockIdx.x * blockDim.x + threadIdx.x;
    if (i >= n) return;
    if (*flag) e32[i] = ((const int*)eraw)[i];
    else       e32[i] = (int)(((const long long*)eraw)[i]);
}

// ---------------------------------------------------------------------------
// Edge MLP (16->6 relu ->3 sigmoid) + degree-1 open B-spline basis.
// Emits fp16 weights (wq[E][8]) and byte kernel indices (kq[E][8]).
// ---------------------------------------------------------------------------
__global__ void edge_basis(const float* __restrict__ ea,
                           const float* __restrict__ Wp1, const float* __restrict__ bp1,
                           const float* __restrict__ Wp2, const float* __restrict__ bp2,
                           ush* __restrict__ wq, uch* __restrict__ kq) {
    __shared__ float sW1[EDGE_DIM * MLP_HID];
    __shared__ float sb1[MLP_HID];
    __shared__ float sW2[MLP_HID * SDIM];
    __shared__ float sb2[SDIM];
    int t = threadIdx.x;
    if (t < EDGE_DIM * MLP_HID) sW1[t] = Wp1[t];
    if (t < MLP_HID)            sb1[t] = bp1[t];
    if (t < MLP_HID * SDIM)     sW2[t] = Wp2[t];
    if (t < SDIM)               sb2[t] = bp2[t];
    __syncthreads();
    int e = blockIdx.x * blockDim.x + t;
    if (e >= E_EDGES) return;

    float a[EDGE_DIM];
#pragma unroll
    for (int i = 0; i < EDGE_DIM; i++) a[i] = ea[(long)e * EDGE_DIM + i];

    float hid[MLP_HID];
#pragma unroll
    for (int j = 0; j < MLP_HID; j++) {
        float s = sb1[j];
#pragma unroll
        for (int i = 0; i < EDGE_DIM; i++) s += a[i] * sW1[i * MLP_HID + j];
        hid[j] = fmaxf(s, 0.f);
    }

    float lo[SDIM], fr[SDIM];
#pragma unroll
    for (int d = 0; d < SDIM; d++) {
        float s = sb2[d];
#pragma unroll
        for (int j = 0; j < MLP_HID; j++) s += hid[j] * sW2[j * SDIM + d];
        float u = 1.f / (1.f + expf(-s));
        float v = u * (float)(KS - 1);
        float l = floorf(v);
        l = fminf(fmaxf(l, 0.f), (float)(KS - 2));
        lo[d] = l;
        fr[d] = v - l;
    }

#pragma unroll
    for (int s = 0; s < S_TAPS; s++) {
        float w = 1.f;
        int idx = 0, stride = 1;
#pragma unroll
        for (int d = 0; d < SDIM; d++) {
            int bit = (s >> d) & 1;
            w *= bit ? fr[d] : (1.f - fr[d]);
            idx += ((int)lo[d] + bit) * stride;
            stride *= KS;
        }
        wq[(long)e * S_TAPS + s] = f2h(w);
        kq[(long)e * S_TAPS + s] = (uch)idx;
    }
}

// ---------------------------------------------------------------------------
// CSR build binned by (dst, src-chunk) — built once, reused for 3 layers
// ---------------------------------------------------------------------------
__global__ void zero_int(int* __restrict__ p, int n) {
    int i = blockIdx.x * blockDim.x + threadIdx.x;
    if (i < n) p[i] = 0;
}

__global__ void hist2_kernel(const int* __restrict__ dst, const int* __restrict__ src,
                             int* __restrict__ hist, int nc, int chunk_rows) {
    int e = blockIdx.x * blockDim.x + threadIdx.x;
    if (e >= E_EDGES) return;
    int bin = dst[e] * nc + src[e] / chunk_rows;
    atomicAdd(&hist[bin], 1);
}

__global__ void scan_kernel(const int* __restrict__ hist, int* __restrict__ rowptr, int B) {
    __shared__ int part[256];
    int t = threadIdx.x;
    const int per = (B + 255) / 256;
    int base = t * per;
    int s = 0;
    for (int i = 0; i < per; i++) {
        int idx = base + i;
        if (idx < B) s += hist[idx];
    }
    part[t] = s;
    __syncthreads();
    for (int off = 1; off < 256; off <<= 1) {
        int v = (t >= off) ? part[t - off] : 0;
        __syncthreads();
        part[t] += v;
        __syncthreads();
    }
    int run = (t == 0) ? 0 : part[t - 1];
    for (int i = 0; i < per; i++) {
        int idx = base + i;
        if (idx < B) { rowptr[idx] = run; run += hist[idx]; }
    }
    if (t == 255) rowptr[B] = run;
}

__global__ void perm2_kernel(const int* __restrict__ dst, const int* __restrict__ src,
                             const int* __restrict__ rowptr, int* __restrict__ cursor,
                             int* __restrict__ eperm, int nc, int chunk_rows) {
    int e = blockIdx.x * blockDim.x + threadIdx.x;
    if (e >= E_EDGES) return;
    int bin = dst[e] * nc + src[e] / chunk_rows;
    int pos = rowptr[bin] + atomicAdd(&cursor[bin], 1);
    eperm[pos] = e;
}

// Pack metadata into CSR order: sequential streaming in the gather.
__global__ void pack_csr(const int* __restrict__ eperm, const int* __restrict__ src,
                         const ush* __restrict__ wq, const uch* __restrict__ kq,
                         int* __restrict__ srcp, ush* __restrict__ wp, uch* __restrict__ kp) {
    int j = blockIdx.x * blockDim.x + threadIdx.x;
    if (j >= E_EDGES) return;
    int e = eperm[j];
    srcp[j] = src[e];
    *(uint4*)(wp + (size_t)j * 8) = *(const uint4*)(wq + (size_t)e * 8);
    *(uint2*)(kp + (size_t)j * 8) = *(const uint2*)(kq + (size_t)e * 8);
}

// ---------------------------------------------------------------------------
// Convert activations -> bf16 hi/lo in MFMA A-fragment layout.
// ---------------------------------------------------------------------------
__global__ void convA_kernel(const float* __restrict__ A, short* __restrict__ hi,
                             short* __restrict__ lo, int do_relu) {
    int gid = blockIdx.x * blockDim.x + threadIdx.x;
    if (gid >= MT_TOTAL * 4 * 64) return;
    int lane = gid & 63;
    int ks = (gid >> 6) & 3;
    int mt = gid >> 8;
    int row = mt * 16 + (lane & 15);
    int col = ks * 32 + ((lane >> 4) & 3) * 8;
    const float* p = A + (long)row * CIN + col;
    long off = ((long)(mt * 4 + ks) * 64 + lane) * 8;
#pragma unroll
    for (int j = 0; j < 8; j++) {
        float v = p[j];
        if (do_relu) v = fmaxf(v, 0.f);
        short h = f2bf(v);
        float r = v - bf2f((unsigned short)h);
        hi[off + j] = h;
        lo[off + j] = f2bf(r);
    }
}

// ---------------------------------------------------------------------------
// Pack [W (27 blocks) | Wr] -> bf16 in MFMA B-fragment layout (hi only).
// ---------------------------------------------------------------------------
__global__ void packW_kernel(const float* __restrict__ W, const float* __restrict__ Wr,
                             short* __restrict__ hi) {
    int gid = blockIdx.x * blockDim.x + threadIdx.x;
    if (gid >= NB * 4 * 8 * 64) return;
    int lane = gid & 63;
    int nt = (gid >> 6) & 7;
    int ks = (gid >> 9) & 3;
    int kb = gid >> 11;
    int i0 = ks * 32 + ((lane >> 4) & 3) * 8;
    int o = nt * 16 + (lane & 15);
    const float* src = (kb < KK) ? (W + (long)kb * 16384 + (long)i0 * 128 + o)
                                 : (Wr + (long)i0 * 128 + o);
    long off = ((long)((kb * 4 + ks) * 8 + nt) * 64 + lane) * 8;
#pragma unroll
    for (int j = 0; j < 8; j++) {
        float v = src[(long)j * 128];
        hi[off + j] = f2bf(v);
    }
}

// ---------------------------------------------------------------------------
// MFMA GEMM: Z[row-row_lo, kb*128+o] = sum_i A[row,i]*B[kb][i][o]  (bf16 out)
// Split-bf16 2-pass on A (AhiB + AloB); W plain bf16.
// grid = (kb=NB fast, m-group) for A-slice L2 locality.
// ---------------------------------------------------------------------------
__global__ __launch_bounds__(256) void gemm_kernel(
    const short* __restrict__ Ah, const short* __restrict__ Al,
    const short* __restrict__ Wh,
    ush* __restrict__ Z, int mtile_lo, int mtile_hi, int row_lo, int row_hi)
{
    int wave = threadIdx.x >> 6;
    int lane = threadIdx.x & 63;
    int kb = blockIdx.x;                               // fast-varying -> A locality
    int mt0 = mtile_lo + blockIdx.y * 8 + wave * 2;
    if (mt0 >= mtile_hi) return;
    int mt1 = (mt0 + 1 < mtile_hi) ? (mt0 + 1) : mt0;

    v4f acc[2][8];
#pragma unroll
    for (int m = 0; m < 2; m++)
#pragma unroll
        for (int n = 0; n < 8; n++) acc[m][n] = (v4f){0.f, 0.f, 0.f, 0.f};

#pragma unroll
    for (int ks = 0; ks < 4; ks++) {
        long a0 = ((long)(mt0 * 4 + ks) * 64 + lane) * 8;
        long a1 = ((long)(mt1 * 4 + ks) * 64 + lane) * 8;
        v8s ah0 = *(const v8s*)(Ah + a0);
        v8s al0 = *(const v8s*)(Al + a0);
        v8s ah1 = *(const v8s*)(Ah + a1);
        v8s al1 = *(const v8s*)(Al + a1);
#pragma unroll
        for (int nt = 0; nt < 8; nt++) {
            long boff = ((long)((kb * 4 + ks) * 8 + nt) * 64 + lane) * 8;
            v8s bh = *(const v8s*)(Wh + boff);
            acc[0][nt] = __builtin_amdgcn_mfma_f32_16x16x32_bf16(ah0, bh, acc[0][nt], 0, 0, 0);
            acc[0][nt] = __builtin_amdgcn_mfma_f32_16x16x32_bf16(al0, bh, acc[0][nt], 0, 0, 0);
            acc[1][nt] = __builtin_amdgcn_mfma_f32_16x16x32_bf16(ah1, bh, acc[1][nt], 0, 0, 0);
            acc[1][nt] = __builtin_amdgcn_mfma_f32_16x16x32_bf16(al1, bh, acc[1][nt], 0, 0, 0);
        }
    }

    // C/D layout: col = lane&15, row-in-tile = (lane>>4)*4 + reg
#pragma unroll
    for (int m = 0; m < 2; m++) {
        int mtg = mt0 + m;
        if (mtg >= mtile_hi) break;
#pragma unroll
        for (int nt = 0; nt < 8; nt++) {
            int col = kb * 128 + nt * 16 + (lane & 15);
#pragma unroll
            for (int r = 0; r < 4; r++) {
                int row = mtg * 16 + ((lane >> 4) & 3) * 4 + r;
                if (row >= row_hi) continue;
                Z[(size_t)(row - row_lo) * ZLD + col] = (ush)f2bf(acc[m][nt][r]);
            }
        }
    }
}

// ---------------------------------------------------------------------------
// Gather v4: one wave per dst node. Taps come in pairs with ADJACENT kernel
// blocks (s=2q,2q+1 differ in the dim-0 bit => k, k+1): the 8x256B random
// reads become 4x512B CONTIGUOUS reads — half the DRAM row activations.
// Lane = (pair p = lane>>4) x (block-bit b = (lane>>3)&1) x (ch-chunk
// g = lane&7, 16 ch). Per edge: 2x dwordx4 per lane. Tap reduction via
// shfl_xor masks 8/16/32; lanes 0-7 add root+bias and store.
// ---------------------------------------------------------------------------
__global__ __launch_bounds__(256) void gather4_kernel(
    const ush* __restrict__ Z, const int* __restrict__ rowptr,
    const int* __restrict__ srcp, const ush* __restrict__ wp,
    const uch* __restrict__ kp, const float* __restrict__ bias,
    float* __restrict__ outp, int lo, int hi, int nc, int cidx, int first)
{
    int wave = threadIdx.x >> 6;
    int lane = threadIdx.x & 63;
    int n = blockIdx.x * 4 + wave;
    int p = lane >> 4;             // tap pair 0..3
    int b = (lane >> 3) & 1;       // block within pair
    int g = lane & 7;              // channel chunk (16 ch)
    int cb = g * 16;

    int bin = n * nc + cidx;
    int jb = rowptr[bin], je = rowptr[bin + 1];

    float acc[16];
#pragma unroll
    for (int i = 0; i < 16; i++) acc[i] = 0.f;

#pragma unroll 2
    for (int j = jb; j < je; j++) {
        int s = srcp[j];
        int kbase = kp[(size_t)j * 8 + 2 * p];          // pair base block
        float w = h2f(wp[(size_t)j * 8 + 2 * p + b]);   // this block's weight
        const ush* zb = Z + (size_t)(s - lo) * ZLD + (kbase + b) * 128 + cb;
        uint4 z0 = *(const uint4*)(zb);       // ch cb+0 .. cb+7
        uint4 z1 = *(const uint4*)(zb + 8);   // ch cb+8 .. cb+15
        acc[0]  += w * bf2f_lo(z0.x);  acc[1]  += w * bf2f_hi(z0.x);
        acc[2]  += w * bf2f_lo(z0.y);  acc[3]  += w * bf2f_hi(z0.y);
        acc[4]  += w * bf2f_lo(z0.z);  acc[5]  += w * bf2f_hi(z0.z);
        acc[6]  += w * bf2f_lo(z0.w);  acc[7]  += w * bf2f_hi(z0.w);
        acc[8]  += w * bf2f_lo(z1.x);  acc[9]  += w * bf2f_hi(z1.x);
        acc[10] += w * bf2f_lo(z1.y);  acc[11] += w * bf2f_hi(z1.y);
        acc[12] += w * bf2f_lo(z1.z);  acc[13] += w * bf2f_hi(z1.z);
        acc[14] += w * bf2f_lo(z1.w);  acc[15] += w * bf2f_hi(z1.w);
    }

    // Reduce over the 8 (pair, block) contributors: lanes differing in bits 3,4,5.
#pragma unroll
    for (int m = 8; m <= 32; m <<= 1) {
#pragma unroll
        for (int i = 0; i < 16; i++) acc[i] += __shfl_xor(acc[i], m, 64);
    }

    if (lane < 8) {                // p==0, b==0 lanes hold the totals
        if (n >= lo && n < hi) {   // root weight + bias (chunk owning node n)
            const ush* zr = Z + (size_t)(n - lo) * ZLD + KK * 128 + cb;
            uint4 r0 = *(const uint4*)(zr);
            uint4 r1 = *(const uint4*)(zr + 8);
            const float4* bp4 = (const float4*)(bias + cb);
            float4 b0 = bp4[0], b1 = bp4[1], b2 = bp4[2], b3 = bp4[3];
            acc[0]  += bf2f_lo(r0.x) + b0.x;  acc[1]  += bf2f_hi(r0.x) + b0.y;
            acc[2]  += bf2f_lo(r0.y) + b0.z;  acc[3]  += bf2f_hi(r0.y) + b0.w;
            acc[4]  += bf2f_lo(r0.z) + b1.x;  acc[5]  += bf2f_hi(r0.z) + b1.y;
            acc[6]  += bf2f_lo(r0.w) + b1.z;  acc[7]  += bf2f_hi(r0.w) + b1.w;
            acc[8]  += bf2f_lo(r1.x) + b2.x;  acc[9]  += bf2f_hi(r1.x) + b2.y;
            acc[10] += bf2f_lo(r1.y) + b2.z;  acc[11] += bf2f_hi(r1.y) + b2.w;
            acc[12] += bf2f_lo(r1.z) + b3.x;  acc[13] += bf2f_hi(r1.z) + b3.y;
            acc[14] += bf2f_lo(r1.w) + b3.z;  acc[15] += bf2f_hi(r1.w) + b3.w;
        }
        float* op = outp + (size_t)n * HDIM + cb;
        if (!first) {
            const float4* o4 = (const float4*)op;
#pragma unroll
            for (int q = 0; q < 4; q++) {
                float4 ov = o4[q];
                acc[q * 4 + 0] += ov.x; acc[q * 4 + 1] += ov.y;
                acc[q * 4 + 2] += ov.z; acc[q * 4 + 3] += ov.w;
            }
        }
#pragma unroll
        for (int q = 0; q < 4; q++) {
            float4 ov = make_float4(acc[q * 4 + 0], acc[q * 4 + 1],
                                    acc[q * 4 + 2], acc[q * 4 + 3]);
            ((float4*)op)[q] = ov;
        }
    }
}

// ---------------------------------------------------------------------------
extern "C" void kernel_launch(void* const* d_in, const int* in_sizes, int n_in,
                              void* d_out, int out_size, void* d_ws, size_t ws_size,
                              hipStream_t stream) {
    const float* x   = (const float*)d_in[0];
    const void*  eix = d_in[1];
    const float* ea  = (const float*)d_in[2];
    const float* Wp1 = (const float*)d_in[3];
    const float* bp1 = (const float*)d_in[4];
    const float* Wp2 = (const float*)d_in[5];
    const float* bp2 = (const float*)d_in[6];
    const float* W[3]  = {(const float*)d_in[7],  (const float*)d_in[10], (const float*)d_in[13]};
    const float* Wr[3] = {(const float*)d_in[8],  (const float*)d_in[11], (const float*)d_in[14]};
    const float* b[3]  = {(const float*)d_in[9],  (const float*)d_in[12], (const float*)d_in[15]};
    float* out = (float*)d_out;

    char* ws = (char*)d_ws;
    size_t off = 0;
    auto walloc = [&](size_t bytes) -> void* {
        void* p = ws + off;
        off = (off + bytes + 255) & ~(size_t)255;
        return p;
    };
    int*   flag   = (int*)  walloc(sizeof(int));
    int*   e32    = (int*)  walloc(sizeof(int) * 2 * E_EDGES);
    ush*   wq     = (ush*)  walloc(sizeof(ush) * (size_t)E_EDGES * 8);
    uch*   kq     = (uch*)  walloc((size_t)E_EDGES * 8);
    float* h0     = (float*)walloc(sizeof(float) * (size_t)N_NODES * HDIM);
    float* h1     = (float*)walloc(sizeof(float) * (size_t)N_NODES * HDIM);
    short* Ah     = (short*)walloc(sizeof(short) * (size_t)N_NODES * CIN);
    short* Al     = (short*)walloc(sizeof(short) * (size_t)N_NODES * CIN);
    short* Wh     = (short*)walloc(sizeof(short) * (size_t)NB * 128 * 128);
    int*   eperm  = (int*)  walloc(sizeof(int) * E_EDGES);
    int*   srcp   = (int*)  walloc(sizeof(int) * E_EDGES);
    ush*   wp     = (ush*)  walloc(sizeof(ush) * (size_t)E_EDGES * 8);
    uch*   kp     = (uch*)  walloc((size_t)E_EDGES * 8);

    // Pick the smallest chunk count nc such that CSR arrays + Z fit.
    int  nc = -1;
    long chunk_rows = 0;
    for (int t = 1; t <= 157; t++) {
        long cr = (((N_NODES + t - 1) / t) + 127) / 128 * 128;
        size_t bins = (size_t)N_NODES * t;
        size_t need = 0;
        auto a = [&](size_t bb) { need += (bb + 255) & ~(size_t)255; };
        a(sizeof(int) * bins);             // hist
        a(sizeof(int) * bins);             // cursor
        a(sizeof(int) * (bins + 1));       // rowptr
        a((size_t)cr * ZLD * sizeof(ush)); // Z
        if (off + need <= ws_size) { nc = t; chunk_rows = cr; break; }
    }
    if (nc < 0) { nc = 157; chunk_rows = 128; }
    size_t bins = (size_t)N_NODES * nc;
    int*   hist   = (int*)walloc(sizeof(int) * bins);
    int*   cursor = (int*)walloc(sizeof(int) * bins);
    int*   rowptr = (int*)walloc(sizeof(int) * (bins + 1));
    ush*   Z      = (ush*)walloc((size_t)chunk_rows * ZLD * sizeof(ush));

    int* srcv = e32;
    int* dstv = e32 + E_EDGES;

    detect_kernel<<<1, 1024, 0, stream>>>((const unsigned int*)eix, flag);
    decode_edges<<<(2 * E_EDGES + 255) / 256, 256, 0, stream>>>(eix, flag, e32, 2 * E_EDGES);
    edge_basis<<<(E_EDGES + 255) / 256, 256, 0, stream>>>(ea, Wp1, bp1, Wp2, bp2, wq, kq);

    // CSR binned by (dst, src-chunk); built once, reused across 3 layers
    zero_int<<<((int)bins + 255) / 256, 256, 0, stream>>>(hist, (int)bins);
    zero_int<<<((int)bins + 255) / 256, 256, 0, stream>>>(cursor, (int)bins);
    hist2_kernel<<<(E_EDGES + 255) / 256, 256, 0, stream>>>(dstv, srcv, hist, nc, (int)chunk_rows);
    scan_kernel<<<1, 256, 0, stream>>>(hist, rowptr, (int)bins);
    perm2_kernel<<<(E_EDGES + 255) / 256, 256, 0, stream>>>(dstv, srcv, rowptr, cursor,
                                                            eperm, nc, (int)chunk_rows);
    pack_csr<<<(E_EDGES + 255) / 256, 256, 0, stream>>>(eperm, srcv, wq, kq, srcp, wp, kp);

    const float* lin[3]  = {x, h0, h1};
    float*       lout[3] = {h0, h1, out};

    for (int l = 0; l < 3; l++) {
        convA_kernel<<<(MT_TOTAL * 4 * 64 + 255) / 256, 256, 0, stream>>>(
            lin[l], Ah, Al, (l > 0) ? 1 : 0);
        packW_kernel<<<(NB * 4 * 8 * 64 + 255) / 256, 256, 0, stream>>>(
            W[l], Wr[l], Wh);
        for (int c = 0; c < nc; c++) {
            long lo = (long)c * chunk_rows;
            long hi = lo + chunk_rows;
            if (hi > N_NODES) hi = N_NODES;
            if (lo >= N_NODES) break;
            int mtile_lo = (int)(lo / 16);
            int mtile_hi = (int)((hi + 15) / 16);
            int gy = (mtile_hi - mtile_lo + 7) / 8;
            dim3 grid(NB, gy);
            gemm_kernel<<<grid, 256, 0, stream>>>(Ah, Al, Wh, Z,
                                                  mtile_lo, mtile_hi, (int)lo, (int)hi);
            gather4_kernel<<<N_NODES / 4, 256, 0, stream>>>(
                Z, rowptr, srcp, wp, kp, b[l], lout[l],
                (int)lo, (int)hi, nc, c, (c == 0) ? 1 : 0);
        }
    }
}

// Round 9
// 644.879 us; speedup vs baseline: 1.0651x; 1.0468x over previous
//
#include <hip/hip_runtime.h>
#include <hip/hip_bf16.h>
#include <hip/hip_fp16.h>

#define N_NODES 20000
#define E_EDGES 320000
#define CIN 128
#define HDIM 128
#define EDGE_DIM 16
#define SDIM 3
#define KS 3
#define KK 27           // 3^3 kernel weight matrices
#define NB 28           // 27 spline blocks + 1 root-weight block
#define ZLD (NB * 128)  // Z leading dim = 3584 elements (bf16)
#define S_TAPS 8
#define MLP_HID 6
#define MT_TOTAL (N_NODES / 16)   // 1250 m-tiles of 16 rows

typedef __attribute__((ext_vector_type(8))) short v8s;   // 8 bf16 (4 VGPRs)
typedef __attribute__((ext_vector_type(4))) float v4f;   // MFMA accumulator
typedef unsigned short ush;
typedef unsigned char uch;

static __device__ __forceinline__ short f2bf(float v) {
    unsigned u = __float_as_uint(v);
    unsigned r = (u + 0x7fffu + ((u >> 16) & 1u)) >> 16;   // RTNE
    return (short)r;
}
static __device__ __forceinline__ float bf2f(unsigned s) {
    return __uint_as_float((s & 0xffffu) << 16);
}
static __device__ __forceinline__ float bf2f_lo(unsigned u) {   // low bf16 of a packed pair
    return __uint_as_float(u << 16);
}
static __device__ __forceinline__ float bf2f_hi(unsigned u) {   // high bf16 of a packed pair
    return __uint_as_float(u & 0xffff0000u);
}
static __device__ __forceinline__ unsigned short f2h(float f) {
    __half h = __float2half(f);
    return __half_as_ushort(h);
}
static __device__ __forceinline__ float h2f(unsigned u) {
    __half_raw r; r.x = (unsigned short)u;
    return __half2float(__half(r));
}

// ---------------------------------------------------------------------------
// edge_index dtype detect + decode (int64 vs int32 storage)
// ---------------------------------------------------------------------------
__global__ void detect_kernel(const unsigned int* __restrict__ e, int* __restrict__ flag) {
    __shared__ int s_nz;
    if (threadIdx.x == 0) s_nz = 0;
    __syncthreads();
    unsigned int v = e[threadIdx.x * 2 + 1];
    if (v != 0) atomicAdd(&s_nz, 1);
    __syncthreads();
    if (threadIdx.x == 0) *flag = (s_nz > 0) ? 1 : 0;
}

__global__ void decode_edges(const void* __restrict__ eraw, const int* __restrict__ flag,
                             int* __restrict__ e32, int n) {
    int i = blockIdx.x * blockDim.x + threadIdx.x;
    if (i >= n) return;
    if (*flag) e32[i] = ((const int*)eraw)[i];
    else       e32[i] = (int)(((const long long*)eraw)[i]);
}

// ---------------------------------------------------------------------------
// Edge MLP (16->6 relu ->3 sigmoid) + degree-1 open B-spline basis.
// Emits fp16 weights (wq[E][8]) and byte kernel indices (kq[E][8]).
// ---------------------------------------------------------------------------
__global__ void edge_basis(const float* __restrict__ ea,
                           const float* __restrict__ Wp1, const float* __restrict__ bp1,
                           const float* __restrict__ Wp2, const float* __restrict__ bp2,
                           ush* __restrict__ wq, uch* __restrict__ kq) {
    __shared__ float sW1[EDGE_DIM * MLP_HID];
    __shared__ float sb1[MLP_HID];
    __shared__ float sW2[MLP_HID * SDIM];
    __shared__ float sb2[SDIM];
    int t = threadIdx.x;
    if (t < EDGE_DIM * MLP_HID) sW1[t] = Wp1[t];
    if (t < MLP_HID)            sb1[t] = bp1[t];
    if (t < MLP_HID * SDIM)     sW2[t] = Wp2[t];
    if (t < SDIM)               sb2[t] = bp2[t];
    __syncthreads();
    int e = blockIdx.x * blockDim.x + t;
    if (e >= E_EDGES) return;

    float a[EDGE_DIM];
#pragma unroll
    for (int i = 0; i < EDGE_DIM; i++) a[i] = ea[(long)e * EDGE_DIM + i];

    float hid[MLP_HID];
#pragma unroll
    for (int j = 0; j < MLP_HID; j++) {
        float s = sb1[j];
#pragma unroll
        for (int i = 0; i < EDGE_DIM; i++) s += a[i] * sW1[i * MLP_HID + j];
        hid[j] = fmaxf(s, 0.f);
    }

    float lo[SDIM], fr[SDIM];
#pragma unroll
    for (int d = 0; d < SDIM; d++) {
        float s = sb2[d];
#pragma unroll
        for (int j = 0; j < MLP_HID; j++) s += hid[j] * sW2[j * SDIM + d];
        float u = 1.f / (1.f + expf(-s));
        float v = u * (float)(KS - 1);
        float l = floorf(v);
        l = fminf(fmaxf(l, 0.f), (float)(KS - 2));
        lo[d] = l;
        fr[d] = v - l;
    }

#pragma unroll
    for (int s = 0; s < S_TAPS; s++) {
        float w = 1.f;
        int idx = 0, stride = 1;
#pragma unroll
        for (int d = 0; d < SDIM; d++) {
            int bit = (s >> d) & 1;
            w *= bit ? fr[d] : (1.f - fr[d]);
            idx += ((int)lo[d] + bit) * stride;
            stride *= KS;
        }
        wq[(long)e * S_TAPS + s] = f2h(w);
        kq[(long)e * S_TAPS + s] = (uch)idx;
    }
}

// ---------------------------------------------------------------------------
// CSR build binned by (dst, src-chunk) — built once, reused for 3 layers
// ---------------------------------------------------------------------------
__global__ void zero_int(int* __restrict__ p, int n) {
    int i = blockIdx.x * blockDim.x + threadIdx.x;
    if (i < n) p[i] = 0;
}

__global__ void hist2_kernel(const int* __restrict__ dst, const int* __restrict__ src,
                             int* __restrict__ hist, int nc, int chunk_rows) {
    int e = blockIdx.x * blockDim.x + threadIdx.x;
    if (e >= E_EDGES) return;
    int bin = dst[e] * nc + src[e] / chunk_rows;
    atomicAdd(&hist[bin], 1);
}

__global__ void scan_kernel(const int* __restrict__ hist, int* __restrict__ rowptr, int B) {
    __shared__ int part[256];
    int t = threadIdx.x;
    const int per = (B + 255) / 256;
    int base = t * per;
    int s = 0;
    for (int i = 0; i < per; i++) {
        int idx = base + i;
        if (idx < B) s += hist[idx];
    }
    part[t] = s;
    __syncthreads();
    for (int off = 1; off < 256; off <<= 1) {
        int v = (t >= off) ? part[t - off] : 0;
        __syncthreads();
        part[t] += v;
        __syncthreads();
    }
    int run = (t == 0) ? 0 : part[t - 1];
    for (int i = 0; i < per; i++) {
        int idx = base + i;
        if (idx < B) { rowptr[idx] = run; run += hist[idx]; }
    }
    if (t == 255) rowptr[B] = run;
}

__global__ void perm2_kernel(const int* __restrict__ dst, const int* __restrict__ src,
                             const int* __restrict__ rowptr, int* __restrict__ cursor,
                             int* __restrict__ eperm, int nc, int chunk_rows) {
    int e = blockIdx.x * blockDim.x + threadIdx.x;
    if (e >= E_EDGES) return;
    int bin = dst[e] * nc + src[e] / chunk_rows;
    int pos = rowptr[bin] + atomicAdd(&cursor[bin], 1);
    eperm[pos] = e;
}

// Pack metadata into CSR order: sequential streaming in the gather.
__global__ void pack_csr(const int* __restrict__ eperm, const int* __restrict__ src,
                         const ush* __restrict__ wq, const uch* __restrict__ kq,
                         int* __restrict__ srcp, ush* __restrict__ wp, uch* __restrict__ kp) {
    int j = blockIdx.x * blockDim.x + threadIdx.x;
    if (j >= E_EDGES) return;
    int e = eperm[j];
    srcp[j] = src[e];
    *(uint4*)(wp + (size_t)j * 8) = *(const uint4*)(wq + (size_t)e * 8);
    *(uint2*)(kp + (size_t)j * 8) = *(const uint2*)(kq + (size_t)e * 8);
}

// ---------------------------------------------------------------------------
// Convert activations -> bf16 (RTNE) in MFMA A-fragment layout (hi only;
// the Alo refinement pass was dropped — its error contribution is below the
// bf16-Z storage quantization already present in the gather).
// ---------------------------------------------------------------------------
__global__ void convA_kernel(const float* __restrict__ A, short* __restrict__ hi,
                             int do_relu) {
    int gid = blockIdx.x * blockDim.x + threadIdx.x;
    if (gid >= MT_TOTAL * 4 * 64) return;
    int lane = gid & 63;
    int ks = (gid >> 6) & 3;
    int mt = gid >> 8;
    int row = mt * 16 + (lane & 15);
    int col = ks * 32 + ((lane >> 4) & 3) * 8;
    const float* p = A + (long)row * CIN + col;
    long off = ((long)(mt * 4 + ks) * 64 + lane) * 8;
#pragma unroll
    for (int j = 0; j < 8; j++) {
        float v = p[j];
        if (do_relu) v = fmaxf(v, 0.f);
        hi[off + j] = f2bf(v);
    }
}

// ---------------------------------------------------------------------------
// Pack [W (27 blocks) | Wr] -> bf16 in MFMA B-fragment layout.
// ---------------------------------------------------------------------------
__global__ void packW_kernel(const float* __restrict__ W, const float* __restrict__ Wr,
                             short* __restrict__ hi) {
    int gid = blockIdx.x * blockDim.x + threadIdx.x;
    if (gid >= NB * 4 * 8 * 64) return;
    int lane = gid & 63;
    int nt = (gid >> 6) & 7;
    int ks = (gid >> 9) & 3;
    int kb = gid >> 11;
    int i0 = ks * 32 + ((lane >> 4) & 3) * 8;
    int o = nt * 16 + (lane & 15);
    const float* src = (kb < KK) ? (W + (long)kb * 16384 + (long)i0 * 128 + o)
                                 : (Wr + (long)i0 * 128 + o);
    long off = ((long)((kb * 4 + ks) * 8 + nt) * 64 + lane) * 8;
#pragma unroll
    for (int j = 0; j < 8; j++) {
        float v = src[(long)j * 128];
        hi[off + j] = f2bf(v);
    }
}

// ---------------------------------------------------------------------------
// MFMA GEMM: Z[row-row_lo, kb*128+o] = sum_i A[row,i]*B[kb][i][o]  (bf16 out)
// Plain bf16 A and W (single pass). grid = (kb fast, m-group) for A locality.
// ---------------------------------------------------------------------------
__global__ __launch_bounds__(256) void gemm_kernel(
    const short* __restrict__ Ah, const short* __restrict__ Wh,
    ush* __restrict__ Z, int mtile_lo, int mtile_hi, int row_lo, int row_hi)
{
    int wave = threadIdx.x >> 6;
    int lane = threadIdx.x & 63;
    int kb = blockIdx.x;                               // fast-varying -> A locality
    int mt0 = mtile_lo + blockIdx.y * 8 + wave * 2;
    if (mt0 >= mtile_hi) return;
    int mt1 = (mt0 + 1 < mtile_hi) ? (mt0 + 1) : mt0;

    v4f acc[2][8];
#pragma unroll
    for (int m = 0; m < 2; m++)
#pragma unroll
        for (int n = 0; n < 8; n++) acc[m][n] = (v4f){0.f, 0.f, 0.f, 0.f};

#pragma unroll
    for (int ks = 0; ks < 4; ks++) {
        long a0 = ((long)(mt0 * 4 + ks) * 64 + lane) * 8;
        long a1 = ((long)(mt1 * 4 + ks) * 64 + lane) * 8;
        v8s ah0 = *(const v8s*)(Ah + a0);
        v8s ah1 = *(const v8s*)(Ah + a1);
#pragma unroll
        for (int nt = 0; nt < 8; nt++) {
            long boff = ((long)((kb * 4 + ks) * 8 + nt) * 64 + lane) * 8;
            v8s bh = *(const v8s*)(Wh + boff);
            acc[0][nt] = __builtin_amdgcn_mfma_f32_16x16x32_bf16(ah0, bh, acc[0][nt], 0, 0, 0);
            acc[1][nt] = __builtin_amdgcn_mfma_f32_16x16x32_bf16(ah1, bh, acc[1][nt], 0, 0, 0);
        }
    }

    // C/D layout: col = lane&15, row-in-tile = (lane>>4)*4 + reg
#pragma unroll
    for (int m = 0; m < 2; m++) {
        int mtg = mt0 + m;
        if (mtg >= mtile_hi) break;
#pragma unroll
        for (int nt = 0; nt < 8; nt++) {
            int col = kb * 128 + nt * 16 + (lane & 15);
#pragma unroll
            for (int r = 0; r < 4; r++) {
                int row = mtg * 16 + ((lane >> 4) & 3) * 4 + r;
                if (row >= row_hi) continue;
                Z[(size_t)(row - row_lo) * ZLD + col] = (ush)f2bf(acc[m][nt][r]);
            }
        }
    }
}

// ---------------------------------------------------------------------------
// Gather v4 (unroll 4): one wave per dst node. Tap pairs hit ADJACENT kernel
// blocks => 4x512B contiguous reads per edge. Lane = (pair p = lane>>4) x
// (block-bit b) x (ch-chunk g, 16 ch). unroll 4 -> ~8 wave-loads in flight.
// Tap reduction via shfl_xor 8/16/32; lanes 0-7 add root+bias and store.
// ---------------------------------------------------------------------------
__global__ __launch_bounds__(256) void gather4_kernel(
    const ush* __restrict__ Z, const int* __restrict__ rowptr,
    const int* __restrict__ srcp, const ush* __restrict__ wp,
    const uch* __restrict__ kp, const float* __restrict__ bias,
    float* __restrict__ outp, int lo, int hi, int nc, int cidx, int first)
{
    int wave = threadIdx.x >> 6;
    int lane = threadIdx.x & 63;
    int n = blockIdx.x * 4 + wave;
    int p = lane >> 4;             // tap pair 0..3
    int b = (lane >> 3) & 1;       // block within pair
    int g = lane & 7;              // channel chunk (16 ch)
    int cb = g * 16;

    int bin = n * nc + cidx;
    int jb = rowptr[bin], je = rowptr[bin + 1];

    float acc[16];
#pragma unroll
    for (int i = 0; i < 16; i++) acc[i] = 0.f;

#pragma unroll 4
    for (int j = jb; j < je; j++) {
        int s = srcp[j];
        int kbase = kp[(size_t)j * 8 + 2 * p];          // pair base block
        float w = h2f(wp[(size_t)j * 8 + 2 * p + b]);   // this block's weight
        const ush* zb = Z + (size_t)(s - lo) * ZLD + (kbase + b) * 128 + cb;
        uint4 z0 = *(const uint4*)(zb);       // ch cb+0 .. cb+7
        uint4 z1 = *(const uint4*)(zb + 8);   // ch cb+8 .. cb+15
        acc[0]  += w * bf2f_lo(z0.x);  acc[1]  += w * bf2f_hi(z0.x);
        acc[2]  += w * bf2f_lo(z0.y);  acc[3]  += w * bf2f_hi(z0.y);
        acc[4]  += w * bf2f_lo(z0.z);  acc[5]  += w * bf2f_hi(z0.z);
        acc[6]  += w * bf2f_lo(z0.w);  acc[7]  += w * bf2f_hi(z0.w);
        acc[8]  += w * bf2f_lo(z1.x);  acc[9]  += w * bf2f_hi(z1.x);
        acc[10] += w * bf2f_lo(z1.y);  acc[11] += w * bf2f_hi(z1.y);
        acc[12] += w * bf2f_lo(z1.z);  acc[13] += w * bf2f_hi(z1.z);
        acc[14] += w * bf2f_lo(z1.w);  acc[15] += w * bf2f_hi(z1.w);
    }

    // Reduce over the 8 (pair, block) contributors: lanes differing in bits 3,4,5.
#pragma unroll
    for (int m = 8; m <= 32; m <<= 1) {
#pragma unroll
        for (int i = 0; i < 16; i++) acc[i] += __shfl_xor(acc[i], m, 64);
    }

    if (lane < 8) {                // p==0, b==0 lanes hold the totals
        if (n >= lo && n < hi) {   // root weight + bias (chunk owning node n)
            const ush* zr = Z + (size_t)(n - lo) * ZLD + KK * 128 + cb;
            uint4 r0 = *(const uint4*)(zr);
            uint4 r1 = *(const uint4*)(zr + 8);
            const float4* bp4 = (const float4*)(bias + cb);
            float4 b0 = bp4[0], b1 = bp4[1], b2 = bp4[2], b3 = bp4[3];
            acc[0]  += bf2f_lo(r0.x) + b0.x;  acc[1]  += bf2f_hi(r0.x) + b0.y;
            acc[2]  += bf2f_lo(r0.y) + b0.z;  acc[3]  += bf2f_hi(r0.y) + b0.w;
            acc[4]  += bf2f_lo(r0.z) + b1.x;  acc[5]  += bf2f_hi(r0.z) + b1.y;
            acc[6]  += bf2f_lo(r0.w) + b1.z;  acc[7]  += bf2f_hi(r0.w) + b1.w;
            acc[8]  += bf2f_lo(r1.x) + b2.x;  acc[9]  += bf2f_hi(r1.x) + b2.y;
            acc[10] += bf2f_lo(r1.y) + b2.z;  acc[11] += bf2f_hi(r1.y) + b2.w;
            acc[12] += bf2f_lo(r1.z) + b3.x;  acc[13] += bf2f_hi(r1.z) + b3.y;
            acc[14] += bf2f_lo(r1.w) + b3.z;  acc[15] += bf2f_hi(r1.w) + b3.w;
        }
        float* op = outp + (size_t)n * HDIM + cb;
        if (!first) {
            const float4* o4 = (const float4*)op;
#pragma unroll
            for (int q = 0; q < 4; q++) {
                float4 ov = o4[q];
                acc[q * 4 + 0] += ov.x; acc[q * 4 + 1] += ov.y;
                acc[q * 4 + 2] += ov.z; acc[q * 4 + 3] += ov.w;
            }
        }
#pragma unroll
        for (int q = 0; q < 4; q++) {
            float4 ov = make_float4(acc[q * 4 + 0], acc[q * 4 + 1],
                                    acc[q * 4 + 2], acc[q * 4 + 3]);
            ((float4*)op)[q] = ov;
        }
    }
}

// ---------------------------------------------------------------------------
extern "C" void kernel_launch(void* const* d_in, const int* in_sizes, int n_in,
                              void* d_out, int out_size, void* d_ws, size_t ws_size,
                              hipStream_t stream) {
    const float* x   = (const float*)d_in[0];
    const void*  eix = d_in[1];
    const float* ea  = (const float*)d_in[2];
    const float* Wp1 = (const float*)d_in[3];
    const float* bp1 = (const float*)d_in[4];
    const float* Wp2 = (const float*)d_in[5];
    const float* bp2 = (const float*)d_in[6];
    const float* W[3]  = {(const float*)d_in[7],  (const float*)d_in[10], (const float*)d_in[13]};
    const float* Wr[3] = {(const float*)d_in[8],  (const float*)d_in[11], (const float*)d_in[14]};
    const float* b[3]  = {(const float*)d_in[9],  (const float*)d_in[12], (const float*)d_in[15]};
    float* out = (float*)d_out;

    char* ws = (char*)d_ws;
    size_t off = 0;
    auto walloc = [&](size_t bytes) -> void* {
        void* p = ws + off;
        off = (off + bytes + 255) & ~(size_t)255;
        return p;
    };
    int*   flag   = (int*)  walloc(sizeof(int));
    int*   e32    = (int*)  walloc(sizeof(int) * 2 * E_EDGES);
    ush*   wq     = (ush*)  walloc(sizeof(ush) * (size_t)E_EDGES * 8);
    uch*   kq     = (uch*)  walloc((size_t)E_EDGES * 8);
    float* h0     = (float*)walloc(sizeof(float) * (size_t)N_NODES * HDIM);
    float* h1     = (float*)walloc(sizeof(float) * (size_t)N_NODES * HDIM);
    short* Ah     = (short*)walloc(sizeof(short) * (size_t)N_NODES * CIN);
    short* Wh     = (short*)walloc(sizeof(short) * (size_t)NB * 128 * 128);
    int*   eperm  = (int*)  walloc(sizeof(int) * E_EDGES);
    int*   srcp   = (int*)  walloc(sizeof(int) * E_EDGES);
    ush*   wp     = (ush*)  walloc(sizeof(ush) * (size_t)E_EDGES * 8);
    uch*   kp     = (uch*)  walloc((size_t)E_EDGES * 8);

    // Pick the smallest chunk count nc such that CSR arrays + Z fit.
    int  nc = -1;
    long chunk_rows = 0;
    for (int t = 1; t <= 157; t++) {
        long cr = (((N_NODES + t - 1) / t) + 127) / 128 * 128;
        size_t bins = (size_t)N_NODES * t;
        size_t need = 0;
        auto a = [&](size_t bb) { need += (bb + 255) & ~(size_t)255; };
        a(sizeof(int) * bins);             // hist
        a(sizeof(int) * bins);             // cursor
        a(sizeof(int) * (bins + 1));       // rowptr
        a((size_t)cr * ZLD * sizeof(ush)); // Z
        if (off + need <= ws_size) { nc = t; chunk_rows = cr; break; }
    }
    if (nc < 0) { nc = 157; chunk_rows = 128; }
    size_t bins = (size_t)N_NODES * nc;
    int*   hist   = (int*)walloc(sizeof(int) * bins);
    int*   cursor = (int*)walloc(sizeof(int) * bins);
    int*   rowptr = (int*)walloc(sizeof(int) * (bins + 1));
    ush*   Z      = (ush*)walloc((size_t)chunk_rows * ZLD * sizeof(ush));

    int* srcv = e32;
    int* dstv = e32 + E_EDGES;

    detect_kernel<<<1, 1024, 0, stream>>>((const unsigned int*)eix, flag);
    decode_edges<<<(2 * E_EDGES + 255) / 256, 256, 0, stream>>>(eix, flag, e32, 2 * E_EDGES);
    edge_basis<<<(E_EDGES + 255) / 256, 256, 0, stream>>>(ea, Wp1, bp1, Wp2, bp2, wq, kq);

    // CSR binned by (dst, src-chunk); built once, reused across 3 layers
    zero_int<<<((int)bins + 255) / 256, 256, 0, stream>>>(hist, (int)bins);
    zero_int<<<((int)bins + 255) / 256, 256, 0, stream>>>(cursor, (int)bins);
    hist2_kernel<<<(E_EDGES + 255) / 256, 256, 0, stream>>>(dstv, srcv, hist, nc, (int)chunk_rows);
    scan_kernel<<<1, 256, 0, stream>>>(hist, rowptr, (int)bins);
    perm2_kernel<<<(E_EDGES + 255) / 256, 256, 0, stream>>>(dstv, srcv, rowptr, cursor,
                                                            eperm, nc, (int)chunk_rows);
    pack_csr<<<(E_EDGES + 255) / 256, 256, 0, stream>>>(eperm, srcv, wq, kq, srcp, wp, kp);

    const float* lin[3]  = {x, h0, h1};
    float*       lout[3] = {h0, h1, out};

    for (int l = 0; l < 3; l++) {
        convA_kernel<<<(MT_TOTAL * 4 * 64 + 255) / 256, 256, 0, stream>>>(
            lin[l], Ah, (l > 0) ? 1 : 0);
        packW_kernel<<<(NB * 4 * 8 * 64 + 255) / 256, 256, 0, stream>>>(
            W[l], Wr[l], Wh);
        for (int c = 0; c < nc; c++) {
            long lo = (long)c * chunk_rows;
            long hi = lo + chunk_rows;
            if (hi > N_NODES) hi = N_NODES;
            if (lo >= N_NODES) break;
            int mtile_lo = (int)(lo / 16);
            int mtile_hi = (int)((hi + 15) / 16);
            int gy = (mtile_hi - mtile_lo + 7) / 8;
            dim3 grid(NB, gy);
            gemm_kernel<<<grid, 256, 0, stream>>>(Ah, Wh, Z,
                                                  mtile_lo, mtile_hi, (int)lo, (int)hi);
            gather4_kernel<<<N_NODES / 4, 256, 0, stream>>>(
                Z, rowptr, srcp, wp, kp, b[l], lout[l],
                (int)lo, (int)hi, nc, c, (c == 0) ? 1 : 0);
        }
    }
}